// Round 3
// baseline (106.113 us; speedup 1.0000x reference)
//
#include <hip/hip_runtime.h>
#include <hip/hip_bf16.h>

// CustomBernsteinLayer: out[b,o] = sum_{i,k} ber[b,i,k] * (coeffs[o,i,k]*weights[o,i])
// ber = (1+t)^k (1-t)^(8-k), t = tanh(x).  With e = exp2(2x*log2e):
//   (1-t) = 2/(e+1) = q, (1+t) = q*e, ratio r = e, p0 = q^8, ber_{k+1} = ber_k * r.
// bf16 MFMA GEMM M=16384 N=256 K=2304.
// Round-3 structure: BARRIER-FREE. A-fragments generated per-lane in registers
// (the mfma A layout row=lane&15, k=(lane>>4)*8+j is exactly per-lane data).
// B (wc, fragment-ready layout) double-buffered in registers from global (L2).
// No LDS, no __syncthreads, 2 blocks/CU x 4 waves -> 2 independent waves/SIMD.

#define BDIM 16384
#define IDIM 256
#define ODIM 256
#define NK 9
#define NCHUNK 4
#define NSTEP 36
#define STEP_ELEMS (ODIM * 64)   // 16384 bf16 (32 KB) per K-step block

typedef short short8 __attribute__((ext_vector_type(8)));
typedef float floatx4 __attribute__((ext_vector_type(4)));

// ---------------------------------------------------------------------------
// prep (validated round 2): wc[step][e] = bf16(coeffs[o,i,k]*weights[o,i]),
// e = (((o>>4)*2 + s)*64 + (o&15) + quad*16)*8 + j, il = s*32+quad*8+j,
// step = (i>>6)*9 + k. One coalesced 16B store per thread.
// ---------------------------------------------------------------------------
__global__ __launch_bounds__(256) void prep_wc2(const float* __restrict__ weights,
                                                const float* __restrict__ coeffs,
                                                ushort* __restrict__ wc) {
    int idx  = blockIdx.x * 256 + threadIdx.x;  // 73728 chunks
    int step = idx >> 11;
    int c    = idx & 2047;
    int big    = c >> 6;
    int lane_w = c & 63;
    int o    = (big >> 1) * 16 + (lane_w & 15);
    int s    = big & 1;
    int quad = lane_w >> 4;
    int ic = step / 9;
    int k  = step - ic * 9;
    int i0 = ic * 64 + s * 32 + quad * 8;

    const float* cp = coeffs + (size_t)(o * IDIM + i0) * NK + k;
    float4 w0 = *(const float4*)(weights + o * IDIM + i0);
    float4 w1 = *(const float4*)(weights + o * IDIM + i0 + 4);
    float wv[8] = {w0.x, w0.y, w0.z, w0.w, w1.x, w1.y, w1.z, w1.w};

    union { ushort us[8]; int4 v; __hip_bfloat162 h2[4]; } pk;
#pragma unroll
    for (int j = 0; j < 8; j += 2) {
        float a = cp[(size_t)j * NK] * wv[j];
        float b = cp[(size_t)(j + 1) * NK] * wv[j + 1];
        pk.h2[j >> 1] = __float22bfloat162_rn(make_float2(a, b));
    }
    *(int4*)(wc + (size_t)step * STEP_ELEMS + (size_t)c * 8) = pk.v;
}

// ---------------------------------------------------------------------------
// GEMM: 512 blocks x 256 threads. Block covers rows row0=blk*32; wave w covers
// cols w*64..w*64+63 (n-tiles nglob = w*4+n). Per lane basis state for its own
// A-fragment slots: (m in {0,1}) rows row0+m*16+(lane&15);
// i_local = s*32 + (lane>>4)*8 + j, s in {0,1}, j in 0..7.
// ---------------------------------------------------------------------------
__global__ __launch_bounds__(256, 2) void bern_gemm(const float* __restrict__ x,
                                                    const ushort* __restrict__ wc,
                                                    float* __restrict__ out) {
    const int tid  = threadIdx.x;
    const int wave = tid >> 6;
    const int lane = tid & 63;
    const int row0 = blockIdx.x * 32;
    const int lrow = lane & 15;
    const int jseg = (lane >> 4) * 8;      // 0,8,16,24

    float p[2][2][8];   // [m][s][j] current Bernstein value (bf16-packed per step)
    float r[2][2][8];   // ratio e = exp2(2x log2 e)
    float xc[2][2][8];  // prefetched x for the NEXT chunk
    floatx4 acc[2][4];
    floatx4 zero = {0.0f, 0.0f, 0.0f, 0.0f};
#pragma unroll
    for (int m = 0; m < 2; ++m)
#pragma unroll
        for (int n = 0; n < 4; ++n)
            acc[m][n] = zero;

    // ---- x chunk loader: xdst[m][s][0..7] = x[row0+m*16+lrow][ic*64+s*32+jseg+j]
#define LOAD_XCHUNK(ic_)                                                        \
    {                                                                           \
        _Pragma("unroll") for (int m = 0; m < 2; ++m)                           \
        _Pragma("unroll") for (int s = 0; s < 2; ++s) {                         \
            const float* xp = x + (size_t)(row0 + m * 16 + lrow) * IDIM         \
                              + (ic_) * 64 + s * 32 + jseg;                     \
            float4 v0 = *(const float4*)(xp);                                   \
            float4 v1 = *(const float4*)(xp + 4);                               \
            xc[m][s][0] = v0.x; xc[m][s][1] = v0.y;                             \
            xc[m][s][2] = v0.z; xc[m][s][3] = v0.w;                             \
            xc[m][s][4] = v1.x; xc[m][s][5] = v1.y;                             \
            xc[m][s][6] = v1.z; xc[m][s][7] = v1.w;                             \
        }                                                                       \
    }

    // ---- basis setup from xc: r = exp2(2x*log2e), p = (2*rcp(r+1))^8
#define SETUP_BASIS()                                                           \
    {                                                                           \
        _Pragma("unroll") for (int m = 0; m < 2; ++m)                           \
        _Pragma("unroll") for (int s = 0; s < 2; ++s)                           \
        _Pragma("unroll") for (int e = 0; e < 8; ++e) {                         \
            float t  = __builtin_amdgcn_exp2f(xc[m][s][e] * 2.8853900817779268f);\
            float q  = 2.0f * __builtin_amdgcn_rcpf(t + 1.0f);                  \
            float q2 = q * q;                                                   \
            float q4 = q2 * q2;                                                 \
            p[m][s][e] = q4 * q4;                                               \
            r[m][s][e] = t;                                                     \
        }                                                                       \
    }

    LOAD_XCHUNK(0);
    SETUP_BASIS();
    LOAD_XCHUNK(1);

    // ---- B register double-buffer; preload step 0 ----
    short8 bfr[2][2][4];   // [buf][s][n]
    {
        const ushort* w0p = wc;
#pragma unroll
        for (int s = 0; s < 2; ++s)
#pragma unroll
            for (int n = 0; n < 4; ++n)
                bfr[0][s][n] = *(const short8*)(w0p + (((wave * 4 + n) * 2 + s) * 64 + lane) * 8);
    }

#pragma unroll
    for (int ic = 0; ic < NCHUNK; ++ic) {
#pragma unroll
        for (int k = 0; k < NK; ++k) {
            const int step = ic * NK + k;
            const int cur  = step & 1;
            const int nxt  = cur ^ 1;

            // prefetch next step's B fragments (in flight across this step's VALU+MFMA)
            if (step + 1 < NSTEP) {
                const ushort* wnp = wc + (size_t)(step + 1) * STEP_ELEMS;
#pragma unroll
                for (int s = 0; s < 2; ++s)
#pragma unroll
                    for (int n = 0; n < 4; ++n)
                        bfr[nxt][s][n] = *(const short8*)(wnp + (((wave * 4 + n) * 2 + s) * 64 + lane) * 8);
            }

            // A fragments: pack current p -> bf16, advance p *= r
            short8 af[2][2];
#pragma unroll
            for (int m = 0; m < 2; ++m)
#pragma unroll
                for (int s = 0; s < 2; ++s) {
                    union { ushort us[8]; short8 v; __hip_bfloat162 h2[4]; } pk;
#pragma unroll
                    for (int e = 0; e < 8; e += 2) {
                        pk.h2[e >> 1] = __float22bfloat162_rn(
                            make_float2(p[m][s][e], p[m][s][e + 1]));
                        p[m][s][e]     *= r[m][s][e];
                        p[m][s][e + 1] *= r[m][s][e + 1];
                    }
                    af[m][s] = pk.v;
                }

            // MFMA 2s x 2m x 4n
#pragma unroll
            for (int s = 0; s < 2; ++s)
#pragma unroll
                for (int m = 0; m < 2; ++m)
#pragma unroll
                    for (int n = 0; n < 4; ++n)
                        acc[m][n] = __builtin_amdgcn_mfma_f32_16x16x32_bf16(
                            af[m][s], bfr[cur][s][n], acc[m][n], 0, 0, 0);
        }

        // chunk boundary: build basis for next chunk, prefetch the one after
        if (ic < NCHUNK - 1) {
            SETUP_BASIS();
            if (ic < NCHUNK - 2) LOAD_XCHUNK(ic + 2);
        }
    }

    // ---- epilogue: C/D layout col=lane&15, row=(lane>>4)*4+reg ----
#pragma unroll
    for (int m = 0; m < 2; ++m) {
#pragma unroll
        for (int n = 0; n < 4; ++n) {
            int col   = wave * 64 + n * 16 + (lane & 15);
            int rbase = row0 + m * 16 + (lane >> 4) * 4;
#pragma unroll
            for (int reg = 0; reg < 4; ++reg) {
                out[(size_t)(rbase + reg) * ODIM + col] = acc[m][n][reg];
            }
        }
    }
#undef LOAD_XCHUNK
#undef SETUP_BASIS
}

extern "C" void kernel_launch(void* const* d_in, const int* in_sizes, int n_in,
                              void* d_out, int out_size, void* d_ws, size_t ws_size,
                              hipStream_t stream) {
    const float* x       = (const float*)d_in[0];   // [B, I]
    const float* weights = (const float*)d_in[1];   // [O, I]
    const float* coeffs  = (const float*)d_in[2];   // [O, I, 9]
    float* out = (float*)d_out;                     // [B, O]
    ushort* wc = (ushort*)d_ws;                     // 36 * 32 KB = 1.13 MB

    prep_wc2<<<288, 256, 0, stream>>>(weights, coeffs, wc);
    bern_gemm<<<BDIM / 32, 256, 0, stream>>>(x, wc, out);
}